// Round 4
// baseline (198.234 us; speedup 1.0000x reference)
//
#include <hip/hip_runtime.h>
#include <hip/hip_bf16.h>

// Head: x[8,2048,768] fp32; Wk,Wq,Wv [768,64] fp32 -> out[8,2048,64] fp32
// q=xWq k=xWk v=xWv; att=softmax(q k^T/8); out=att v   (no causal mask)
//
// R4: fill the SIMDs.
//  - attn: 1024 blocks x 8 waves (512 thr); wave w owns keys [256w,256w+256);
//    32 waves/CU (8/SIMD) via VGPR<=64 + LDS union (P-buf aliases O-combine).
//  - proj: o-split (3072 x 1 wave) with same-CU x sharing (o=bid>>10) and
//    2-step-ahead triple-buffered x prefetch (HBM latency hidden).

#define BATCH 8
#define SEQ   2048
#define CEMB  768
#define HEADD 64
// 0.125 (1/sqrt(64)) * log2(e): pre-scale logits so exp2 is direct
#define SCL 0.18033688011112042f

typedef __attribute__((ext_vector_type(4))) float f32x4;
typedef __attribute__((ext_vector_type(8))) short short8;
typedef __attribute__((ext_vector_type(4))) float fvec4;
typedef __attribute__((ext_vector_type(2))) float fvec2;

__device__ __forceinline__ unsigned short f2bf(float f) {
    unsigned int u = __builtin_bit_cast(unsigned int, f);
    u += 0x7fffu + ((u >> 16) & 1u);   // round-to-nearest-even
    return (unsigned short)(u >> 16);
}

// ---------------- kernel 1: W -> W^T bf16  (wt[3][64][768]) ----------------
__global__ void wt_kernel(const float* __restrict__ Wq, const float* __restrict__ Wk,
                          const float* __restrict__ Wv, unsigned short* __restrict__ wt) {
    int idx = blockIdx.x * 256 + threadIdx.x;   // 3*64*768 = 147456
    int o = idx / 49152;
    int r = idx % 49152;
    int n = r / 768;
    int k = r % 768;
    const float* W = (o == 0) ? Wq : (o == 1) ? Wk : Wv;
    wt[idx] = f2bf(W[k * 64 + n]);
}

// ------ kernel 2: projections, 1 wave = 16 rows x one output matrix -------
__global__ __launch_bounds__(64) void proj_kernel(
        const float* __restrict__ x, const unsigned short* __restrict__ wt,
        unsigned short* __restrict__ qg, unsigned short* __restrict__ kg,
        unsigned short* __restrict__ vtg) {
    __shared__ __align__(16) unsigned short lds[64][20];

    const int lane = threadIdx.x & 63;
    const int l15 = lane & 15;
    const int lq = lane >> 4;
    const int bid = blockIdx.x;
    const int o = bid >> 10;               // 0=q 1=k 2=v
    const int tile = bid & 1023;
    const int row0 = tile * 16;

    f32x4 acc[4];
    #pragma unroll
    for (int f = 0; f < 4; ++f) acc[f] = f32x4{0.f, 0.f, 0.f, 0.f};

    const unsigned short* wbase = wt + o * 49152;
    const float* xbase = &x[(size_t)(row0 + l15) * CEMB + lq * 8];

    fvec4 xb[3][4];
    #define LOADX(SLOT, S) do {                                             \
        const float* xp_ = xbase + (S) * 64;                                \
        xb[SLOT][0] = *reinterpret_cast<const fvec4*>(xp_);                 \
        xb[SLOT][1] = *reinterpret_cast<const fvec4*>(xp_ + 4);             \
        xb[SLOT][2] = *reinterpret_cast<const fvec4*>(xp_ + 32);            \
        xb[SLOT][3] = *reinterpret_cast<const fvec4*>(xp_ + 36);            \
    } while (0)

    LOADX(0, 0);
    LOADX(1, 1);

    #pragma unroll
    for (int step = 0; step < 12; ++step) {
        const int cur = step % 3;
        if (step + 2 < 12) LOADX((step + 2) % 3, step + 2);

        short8 a0, a1;
        #pragma unroll
        for (int j = 0; j < 4; ++j) {
            a0[j]     = (short)f2bf(xb[cur][0][j]);
            a0[4 + j] = (short)f2bf(xb[cur][1][j]);
            a1[j]     = (short)f2bf(xb[cur][2][j]);
            a1[4 + j] = (short)f2bf(xb[cur][3][j]);
        }
        const int k0 = step * 64;
        #pragma unroll
        for (int f = 0; f < 4; ++f) {
            const unsigned short* wp = &wbase[(f * 16 + l15) * CEMB + k0 + lq * 8];
            short8 b0 = *reinterpret_cast<const short8*>(wp);
            short8 b1 = *reinterpret_cast<const short8*>(wp + 32);
            acc[f] = __builtin_amdgcn_mfma_f32_16x16x32_bf16(a0, b0, acc[f], 0, 0, 0);
            acc[f] = __builtin_amdgcn_mfma_f32_16x16x32_bf16(a1, b1, acc[f], 0, 0, 0);
        }
    }
    #undef LOADX

    if (o < 2) {
        // q,k row-major: repack through LDS -> coalesced 16B stores
        unsigned short* dst = o ? kg : qg;
        unsigned short (*lq16)[80] = reinterpret_cast<unsigned short (*)[80]>(&lds[0][0]);
        #pragma unroll
        for (int f = 0; f < 4; ++f)
            #pragma unroll
            for (int r = 0; r < 4; ++r)
                lq16[lq * 4 + r][f * 16 + l15] = f2bf(acc[f][r]);
        __syncthreads();
        #pragma unroll
        for (int i = 0; i < 2; ++i) {
            int chunk = lane + 64 * i;
            int m = chunk >> 3;
            int c0 = (chunk & 7) * 8;
            *reinterpret_cast<short8*>(&dst[(size_t)(row0 + m) * 64 + c0]) =
                *reinterpret_cast<const short8*>(&lq16[m][c0]);
        }
    } else {
        // v transposed: vtg[b][h][t]
        #pragma unroll
        for (int f = 0; f < 4; ++f)
            #pragma unroll
            for (int r = 0; r < 4; ++r)
                lds[f * 16 + l15][lq * 4 + r] = f2bf(acc[f][r]);   // lds[h][m]
        __syncthreads();
        const int bb = row0 >> 11;
        const int t0 = row0 & 2047;
        unsigned short* vp = &vtg[(size_t)bb * 64 * SEQ + (size_t)lane * SEQ + t0];
        *reinterpret_cast<short8*>(vp)     = *reinterpret_cast<const short8*>(&lds[lane][0]);
        *reinterpret_cast<short8*>(vp + 8) = *reinterpret_cast<const short8*>(&lds[lane][8]);
    }
}

// ---- kernel 3: flash attention, 8 waves/block split SEQ, LDS combine -----
__global__ __launch_bounds__(512, 8) void attn_kernel(
        const unsigned short* __restrict__ qg, const unsigned short* __restrict__ kg,
        const unsigned short* __restrict__ vtg, float* __restrict__ out) {
    // union: pl (8 waves x [16][72] ushort = 18432 B) aliases oL
    // (8 x 16 x 64 f32 = 32768 B). One barrier separates the phases.
    __shared__ __align__(16) float smem[8 * 16 * 64];
    __shared__ float mL[8][16];
    __shared__ float lL[8][16];

    const int tid = threadIdx.x;
    const int lane = tid & 63;
    const int wv = tid >> 6;           // wave 0..7: key chunk [256*wv, +256)
    const int l15 = lane & 15;
    const int lq = lane >> 4;

    unsigned short (*pl)[72] =
        reinterpret_cast<unsigned short (*)[72]>(&smem[0]) + wv * 16;
    float (*oL)[16][64] = reinterpret_cast<float (*)[16][64]>(&smem[0]);

    // XCD swizzle: 1024 blocks, 8 XCDs -> each XCD gets one batch (128 blocks)
    const int swz = (blockIdx.x & 7) * 128 + (blockIdx.x >> 3);
    const int b = swz >> 7;            // batch 0..7
    const int qt = swz & 127;          // 16-row query tile
    const size_t qrow0 = (size_t)b * SEQ + (size_t)qt * 16;

    const unsigned short* kbase = &kg[((size_t)b * SEQ + (size_t)wv * 256) * 64];
    const unsigned short* vbase = &vtg[(size_t)b * 64 * SEQ + (size_t)wv * 256];

    const short8 a0 = *reinterpret_cast<const short8*>(&qg[(qrow0 + l15) * 64 + lq * 8]);
    const short8 a1 = *reinterpret_cast<const short8*>(&qg[(qrow0 + l15) * 64 + 32 + lq * 8]);

    f32x4 o_acc[4];
    #pragma unroll
    for (int f = 0; f < 4; ++f) o_acc[f] = f32x4{0.f, 0.f, 0.f, 0.f};
    float m_run[4], l_run[4];
    #pragma unroll
    for (int r = 0; r < 4; ++r) { m_run[r] = -1e30f; l_run[r] = 0.f; }

    for (int kt = 0; kt < 4; ++kt) {
        const unsigned short* kp = kbase + (size_t)kt * 64 * 64;
        const unsigned short* vp = vbase + (size_t)kt * 64;
        short8 kf[8], vf[8];
        #pragma unroll
        for (int f = 0; f < 4; ++f) {
            kf[2 * f]     = *reinterpret_cast<const short8*>(&kp[(f * 16 + l15) * 64 + lq * 8]);
            kf[2 * f + 1] = *reinterpret_cast<const short8*>(&kp[(f * 16 + l15) * 64 + 32 + lq * 8]);
        }
        #pragma unroll
        for (int f = 0; f < 4; ++f) {
            vf[2 * f]     = *reinterpret_cast<const short8*>(&vp[(size_t)(f * 16 + l15) * SEQ + lq * 8]);
            vf[2 * f + 1] = *reinterpret_cast<const short8*>(&vp[(size_t)(f * 16 + l15) * SEQ + 32 + lq * 8]);
        }

        f32x4 s[4];
        #pragma unroll
        for (int f = 0; f < 4; ++f) {
            s[f] = f32x4{0.f, 0.f, 0.f, 0.f};
            s[f] = __builtin_amdgcn_mfma_f32_16x16x32_bf16(a0, kf[2 * f], s[f], 0, 0, 0);
            s[f] = __builtin_amdgcn_mfma_f32_16x16x32_bf16(a1, kf[2 * f + 1], s[f], 0, 0, 0);
        }
        #pragma unroll
        for (int f = 0; f < 4; ++f) s[f] *= SCL;

        float mnew[4], alpha[4], rsum[4];
        #pragma unroll
        for (int r = 0; r < 4; ++r) {
            float mx = fmaxf(fmaxf(s[0][r], s[1][r]), fmaxf(s[2][r], s[3][r]));
            mx = fmaxf(mx, __shfl_xor(mx, 1));
            mx = fmaxf(mx, __shfl_xor(mx, 2));
            mx = fmaxf(mx, __shfl_xor(mx, 4));
            mx = fmaxf(mx, __shfl_xor(mx, 8));
            mnew[r] = fmaxf(m_run[r], mx);
            alpha[r] = exp2f(m_run[r] - mnew[r]);
            m_run[r] = mnew[r];
            rsum[r] = 0.f;
        }
        #pragma unroll
        for (int f = 0; f < 4; ++f)
            #pragma unroll
            for (int r = 0; r < 4; ++r) {
                float pv = exp2f(s[f][r] - mnew[r]);
                rsum[r] += pv;
                pl[lq * 4 + r][f * 16 + l15] = f2bf(pv);
            }
        #pragma unroll
        for (int r = 0; r < 4; ++r) {
            rsum[r] += __shfl_xor(rsum[r], 1);
            rsum[r] += __shfl_xor(rsum[r], 2);
            rsum[r] += __shfl_xor(rsum[r], 4);
            rsum[r] += __shfl_xor(rsum[r], 8);
            l_run[r] = l_run[r] * alpha[r] + rsum[r];
        }
        #pragma unroll
        for (int f = 0; f < 4; ++f)
            #pragma unroll
            for (int r = 0; r < 4; ++r) o_acc[f][r] *= alpha[r];

        short8 pa0 = *reinterpret_cast<const short8*>(&pl[l15][lq * 8]);
        short8 pa1 = *reinterpret_cast<const short8*>(&pl[l15][32 + lq * 8]);
        #pragma unroll
        for (int f = 0; f < 4; ++f) {
            o_acc[f] = __builtin_amdgcn_mfma_f32_16x16x32_bf16(pa0, vf[2 * f], o_acc[f], 0, 0, 0);
            o_acc[f] = __builtin_amdgcn_mfma_f32_16x16x32_bf16(pa1, vf[2 * f + 1], o_acc[f], 0, 0, 0);
        }
    }

    // ---- all waves done with pl; switch the union to oL ----
    __syncthreads();
    #pragma unroll
    for (int r = 0; r < 4; ++r) {
        mL[wv][lq * 4 + r] = m_run[r];
        lL[wv][lq * 4 + r] = l_run[r];
    }
    #pragma unroll
    for (int f = 0; f < 4; ++f)
        #pragma unroll
        for (int r = 0; r < 4; ++r)
            oL[wv][lq * 4 + r][f * 16 + l15] = o_acc[f][r];
    __syncthreads();

    // combine 8 partials: 512 threads cover 16 rows x 32 col-pairs
    const int row = tid >> 5;          // 0..15
    const int c0 = (tid & 31) * 2;     // 0,2,...,62
    float M = mL[0][row];
    #pragma unroll
    for (int w = 1; w < 8; ++w) M = fmaxf(M, mL[w][row]);
    float L = 0.f;
    fvec2 o = {0.f, 0.f};
    #pragma unroll
    for (int w = 0; w < 8; ++w) {
        float sc = exp2f(mL[w][row] - M);
        L += lL[w][row] * sc;
        fvec2 ov = *reinterpret_cast<const fvec2*>(&oL[w][row][c0]);
        o += ov * sc;
    }
    float inv = 1.0f / L;
    o *= inv;
    *reinterpret_cast<fvec2*>(&out[(qrow0 + row) * 64 + c0]) = o;
}

extern "C" void kernel_launch(void* const* d_in, const int* in_sizes, int n_in,
                              void* d_out, int out_size, void* d_ws, size_t ws_size,
                              hipStream_t stream) {
    (void)in_sizes; (void)n_in; (void)out_size; (void)ws_size;
    const float* x  = (const float*)d_in[0];
    const float* Wk = (const float*)d_in[1];   // setup_inputs order: x, Wk, Wq, Wv
    const float* Wq = (const float*)d_in[2];
    const float* Wv = (const float*)d_in[3];
    float* out = (float*)d_out;

    unsigned short* ws = (unsigned short*)d_ws;
    unsigned short* qg  = ws;                      // 16384*64
    unsigned short* kg  = ws + 1048576;            // 16384*64
    unsigned short* vtg = ws + 2097152;            // 8*64*2048
    unsigned short* wt  = ws + 3145728;            // 3*64*768

    wt_kernel<<<576, 256, 0, stream>>>(Wq, Wk, Wv, wt);
    proj_kernel<<<3072, 64, 0, stream>>>(x, wt, qg, kg, vtg);
    attn_kernel<<<1024, 512, 0, stream>>>(qg, kg, vtg, out);
}

// Round 5
// 124.622 us; speedup vs baseline: 1.5907x; 1.5907x over previous
//
#include <hip/hip_runtime.h>
#include <hip/hip_bf16.h>

// Head: x[8,2048,768] fp32; Wk,Wq,Wv [768,64] fp32 -> out[8,2048,64] fp32
// q=xWq k=xWk v=xWv; att=softmax(q k^T/8); out=att v   (no causal mask)
//
// R5: cut L2 traffic.
//  - attn: 512 blocks x 2 waves (32 q-rows); K/V 64-key tiles double-buffered
//    in LDS via global_load_lds with pre-swizzled source + XOR-swizzled reads.
//    One barrier per K-tile. K/V L2 traffic 512->256 MB, coalesced.
//  - proj: o-split (3072 x 1 wave); wave's 16x768 x-slab staged ONCE into
//    swizzled LDS (coalesced); k-loop is barrier-free (LDS A + global W).

#define SEQ   2048
#define CEMB  768
// 0.125 (1/sqrt(64)) * log2(e): pre-scale logits so exp2 is direct
#define SCL 0.18033688011112042f

typedef __attribute__((ext_vector_type(4))) float f32x4;
typedef __attribute__((ext_vector_type(8))) short short8;
typedef __attribute__((ext_vector_type(4))) float fvec4;
typedef __attribute__((ext_vector_type(4))) unsigned short u16x4;

__device__ __forceinline__ unsigned short f2bf(float f) {
    unsigned int u = __builtin_bit_cast(unsigned int, f);
    u += 0x7fffu + ((u >> 16) & 1u);   // round-to-nearest-even
    return (unsigned short)(u >> 16);
}

// async global->LDS, 16B per lane; lds base must be wave-uniform
__device__ __forceinline__ void gl_lds16(const void* g, void* l) {
    __builtin_amdgcn_global_load_lds(
        (const __attribute__((address_space(1))) unsigned int*)g,
        (__attribute__((address_space(3))) unsigned int*)l, 16, 0, 0);
}

// ---------------- kernel 1: W -> W^T bf16  (wt[3][64][768]) ----------------
__global__ void wt_kernel(const float* __restrict__ Wq, const float* __restrict__ Wk,
                          const float* __restrict__ Wv, unsigned short* __restrict__ wt) {
    int idx = blockIdx.x * 256 + threadIdx.x;   // 3*64*768 = 147456
    int o = idx / 49152;
    int r = idx % 49152;
    int n = r / 768;
    int k = r % 768;
    const float* W = (o == 0) ? Wq : (o == 1) ? Wk : Wv;
    wt[idx] = f2bf(W[k * 64 + n]);
}

// ------ kernel 2: projections, 1 wave = 16 rows x one output matrix -------
__global__ __launch_bounds__(64) void proj_kernel(
        const float* __restrict__ x, const unsigned short* __restrict__ wt,
        unsigned short* __restrict__ qg, unsigned short* __restrict__ kg,
        unsigned short* __restrict__ vtg) {
    __shared__ __align__(16) unsigned short xl[16 * 768];   // 24 KB, XOR-swizzled

    const int lane = threadIdx.x & 63;
    const int l15 = lane & 15;
    const int lq = lane >> 4;
    const int bid = blockIdx.x;
    const int tile = bid / 3;
    const int o = bid - tile * 3;          // 0=q 1=k 2=v
    const int row0 = tile * 16;

    // ---- stage x[row0..+16][0..768] fp32 -> bf16 swizzled LDS (coalesced) ----
    {
        const float* xs = &x[(size_t)row0 * CEMB];
        char* xb = (char*)xl;
        #pragma unroll
        for (int m = 0; m < 16; ++m) {
            #pragma unroll
            for (int t = 0; t < 3; ++t) {
                const int col = t * 256 + lane * 4;
                fvec4 v = *reinterpret_cast<const fvec4*>(&xs[(size_t)m * CEMB + col]);
                u16x4 u;
                u[0] = f2bf(v[0]); u[1] = f2bf(v[1]); u[2] = f2bf(v[2]); u[3] = f2bf(v[3]);
                const int byte = m * 1536 + ((col * 2) ^ ((m & 7) << 4));
                *reinterpret_cast<u16x4*>(xb + byte) = u;
            }
        }
    }
    __syncthreads();

    f32x4 acc[4];
    #pragma unroll
    for (int f = 0; f < 4; ++f) acc[f] = f32x4{0.f, 0.f, 0.f, 0.f};

    const unsigned short* wbase = wt + o * 49152;
    const char* xb = (const char*)xl;
    const int rb = l15 * 1536;
    const int rswz = (l15 & 7) << 4;

    #pragma unroll
    for (int step = 0; step < 12; ++step) {
        const int k0 = step * 64;
        short8 a0 = *reinterpret_cast<const short8*>(xb + rb + ((k0 * 2 + lq * 16) ^ rswz));
        short8 a1 = *reinterpret_cast<const short8*>(xb + rb + ((k0 * 2 + 64 + lq * 16) ^ rswz));
        #pragma unroll
        for (int f = 0; f < 4; ++f) {
            const unsigned short* wp = &wbase[(f * 16 + l15) * CEMB + k0 + lq * 8];
            short8 b0 = *reinterpret_cast<const short8*>(wp);
            short8 b1 = *reinterpret_cast<const short8*>(wp + 32);
            acc[f] = __builtin_amdgcn_mfma_f32_16x16x32_bf16(a0, b0, acc[f], 0, 0, 0);
            acc[f] = __builtin_amdgcn_mfma_f32_16x16x32_bf16(a1, b1, acc[f], 0, 0, 0);
        }
    }

    __syncthreads();   // reuse xl as epilogue scratch
    if (o < 2) {
        // q,k row-major: repack through LDS -> coalesced 16B stores
        unsigned short* dst = o ? kg : qg;
        unsigned short (*lq16)[80] = reinterpret_cast<unsigned short (*)[80]>(xl);
        #pragma unroll
        for (int f = 0; f < 4; ++f)
            #pragma unroll
            for (int r = 0; r < 4; ++r)
                lq16[lq * 4 + r][f * 16 + l15] = f2bf(acc[f][r]);
        __syncthreads();
        #pragma unroll
        for (int i = 0; i < 2; ++i) {
            int chunk = lane + 64 * i;
            int m = chunk >> 3;
            int c0 = (chunk & 7) * 8;
            *reinterpret_cast<short8*>(&dst[(size_t)(row0 + m) * 64 + c0]) =
                *reinterpret_cast<const short8*>(&lq16[m][c0]);
        }
    } else {
        // v transposed: vtg[b][h][t]
        unsigned short (*lv)[20] = reinterpret_cast<unsigned short (*)[20]>(xl);
        #pragma unroll
        for (int f = 0; f < 4; ++f)
            #pragma unroll
            for (int r = 0; r < 4; ++r)
                lv[f * 16 + l15][lq * 4 + r] = f2bf(acc[f][r]);   // lv[h][m]
        __syncthreads();
        const int bb = row0 >> 11;
        const int t0 = row0 & 2047;
        unsigned short* vp = &vtg[(size_t)bb * 64 * SEQ + (size_t)lane * SEQ + t0];
        *reinterpret_cast<short8*>(vp)     = *reinterpret_cast<const short8*>(&lv[lane][0]);
        *reinterpret_cast<short8*>(vp + 8) = *reinterpret_cast<const short8*>(&lv[lane][8]);
    }
}

// ---- kernel 3: flash attention, LDS-shared K/V tiles, double-buffered ----
__global__ __launch_bounds__(128) void attn_kernel(
        const unsigned short* __restrict__ qg, const unsigned short* __restrict__ kg,
        const unsigned short* __restrict__ vtg, float* __restrict__ out) {
    __shared__ __align__(16) unsigned short kbuf[2][4096];   // [64 keys][64 d] swz
    __shared__ __align__(16) unsigned short vbuf[2][4096];   // [64 d][64 keys] swz
    __shared__ __align__(16) unsigned short pl[2][16][80];

    const int tid = threadIdx.x;
    const int lane = tid & 63;
    const int wv = tid >> 6;          // 2 waves, 16 q-rows each
    const int l15 = lane & 15;
    const int lq = lane >> 4;

    // XCD swizzle (512 % 8 == 0 -> bijective)
    const int swz = (blockIdx.x & 7) * 64 + (blockIdx.x >> 3);
    const int b = swz >> 6;           // batch 0..7
    const int qt = swz & 63;          // 32-row query tile 0..63
    const size_t qrow0 = (size_t)b * SEQ + (size_t)qt * 32 + (size_t)wv * 16;

    const unsigned short* kbase = kg + (size_t)b * SEQ * 64;
    const unsigned short* vbase = vtg + (size_t)b * 64 * SEQ;

    const short8 a0 = *reinterpret_cast<const short8*>(&qg[(qrow0 + l15) * 64 + lq * 8]);
    const short8 a1 = *reinterpret_cast<const short8*>(&qg[(qrow0 + l15) * 64 + 32 + lq * 8]);

    // stage K/V tile KT into buffer S; src pre-swizzled so linear LDS writes
    // land such that read addr (slot ^ (row&7)) returns logical slot
    #define STAGE(S, KT) do {                                                      \
        _Pragma("unroll")                                                          \
        for (int i_ = 0; i_ < 4; ++i_) {                                           \
            int si_ = i_ * 128 + tid;                                              \
            int row_ = si_ >> 3;                                                   \
            int sl_ = si_ & 7;                                                     \
            const unsigned short* gk_ =                                            \
                kbase + (KT) * 4096 + row_ * 64 + ((sl_ ^ (row_ & 7)) * 8);        \
            gl_lds16(gk_, &kbuf[S][(i_ * 128 + wv * 64) * 8]);                     \
            const unsigned short* gv_ =                                            \
                vbase + (size_t)row_ * SEQ + (KT) * 64 + ((sl_ ^ (row_ & 7)) * 8); \
            gl_lds16(gv_, &vbuf[S][(i_ * 128 + wv * 64) * 8]);                     \
        }                                                                          \
    } while (0)

    f32x4 o_acc[4];
    #pragma unroll
    for (int f = 0; f < 4; ++f) o_acc[f] = f32x4{0.f, 0.f, 0.f, 0.f};
    float m_run[4], l_run[4];
    #pragma unroll
    for (int r = 0; r < 4; ++r) { m_run[r] = -1e30f; l_run[r] = 0.f; }

    STAGE(0, 0);
    __syncthreads();

    for (int kt = 0; kt < 32; ++kt) {
        const int cur = kt & 1;
        if (kt + 1 < 32) STAGE(cur ^ 1, kt + 1);

        short8 kf[8], vf[8];
        #pragma unroll
        for (int f = 0; f < 4; ++f) {
            const int rr = f * 16 + l15;
            const char* kr = (const char*)&kbuf[cur][rr * 64];
            const char* vr = (const char*)&vbuf[cur][rr * 64];
            const int s0 = (lq ^ (rr & 7)) * 16;
            const int s1 = ((lq + 4) ^ (rr & 7)) * 16;
            kf[2 * f]     = *reinterpret_cast<const short8*>(kr + s0);
            kf[2 * f + 1] = *reinterpret_cast<const short8*>(kr + s1);
            vf[2 * f]     = *reinterpret_cast<const short8*>(vr + s0);
            vf[2 * f + 1] = *reinterpret_cast<const short8*>(vr + s1);
        }

        f32x4 s[4];
        #pragma unroll
        for (int f = 0; f < 4; ++f) {
            s[f] = f32x4{0.f, 0.f, 0.f, 0.f};
            s[f] = __builtin_amdgcn_mfma_f32_16x16x32_bf16(a0, kf[2 * f], s[f], 0, 0, 0);
            s[f] = __builtin_amdgcn_mfma_f32_16x16x32_bf16(a1, kf[2 * f + 1], s[f], 0, 0, 0);
        }
        #pragma unroll
        for (int f = 0; f < 4; ++f) s[f] *= SCL;

        float mnew[4], alpha[4], rsum[4];
        #pragma unroll
        for (int r = 0; r < 4; ++r) {
            float mx = fmaxf(fmaxf(s[0][r], s[1][r]), fmaxf(s[2][r], s[3][r]));
            mx = fmaxf(mx, __shfl_xor(mx, 1));
            mx = fmaxf(mx, __shfl_xor(mx, 2));
            mx = fmaxf(mx, __shfl_xor(mx, 4));
            mx = fmaxf(mx, __shfl_xor(mx, 8));
            mnew[r] = fmaxf(m_run[r], mx);
            alpha[r] = exp2f(m_run[r] - mnew[r]);
            m_run[r] = mnew[r];
            rsum[r] = 0.f;
        }
        #pragma unroll
        for (int f = 0; f < 4; ++f)
            #pragma unroll
            for (int r = 0; r < 4; ++r) {
                float pv = exp2f(s[f][r] - mnew[r]);
                rsum[r] += pv;
                pl[wv][lq * 4 + r][f * 16 + l15] = f2bf(pv);
            }
        #pragma unroll
        for (int r = 0; r < 4; ++r) {
            rsum[r] += __shfl_xor(rsum[r], 1);
            rsum[r] += __shfl_xor(rsum[r], 2);
            rsum[r] += __shfl_xor(rsum[r], 4);
            rsum[r] += __shfl_xor(rsum[r], 8);
            l_run[r] = l_run[r] * alpha[r] + rsum[r];
        }
        #pragma unroll
        for (int f = 0; f < 4; ++f)
            #pragma unroll
            for (int r = 0; r < 4; ++r) o_acc[f][r] *= alpha[r];

        short8 pa0 = *reinterpret_cast<const short8*>(&pl[wv][l15][lq * 8]);
        short8 pa1 = *reinterpret_cast<const short8*>(&pl[wv][l15][32 + lq * 8]);
        #pragma unroll
        for (int f = 0; f < 4; ++f) {
            o_acc[f] = __builtin_amdgcn_mfma_f32_16x16x32_bf16(pa0, vf[2 * f], o_acc[f], 0, 0, 0);
            o_acc[f] = __builtin_amdgcn_mfma_f32_16x16x32_bf16(pa1, vf[2 * f + 1], o_acc[f], 0, 0, 0);
        }
        __syncthreads();   // staged tile kt+1 ready; pl reuse safe (wave-local)
    }
    #undef STAGE

    #pragma unroll
    for (int r = 0; r < 4; ++r) {
        float inv = 1.0f / l_run[r];
        #pragma unroll
        for (int f = 0; f < 4; ++f)
            out[(qrow0 + lq * 4 + r) * 64 + f * 16 + l15] = o_acc[f][r] * inv;
    }
}

extern "C" void kernel_launch(void* const* d_in, const int* in_sizes, int n_in,
                              void* d_out, int out_size, void* d_ws, size_t ws_size,
                              hipStream_t stream) {
    (void)in_sizes; (void)n_in; (void)out_size; (void)ws_size;
    const float* x  = (const float*)d_in[0];
    const float* Wk = (const float*)d_in[1];   // setup_inputs order: x, Wk, Wq, Wv
    const float* Wq = (const float*)d_in[2];
    const float* Wv = (const float*)d_in[3];
    float* out = (float*)d_out;

    unsigned short* ws = (unsigned short*)d_ws;
    unsigned short* qg  = ws;                      // 16384*64
    unsigned short* kg  = ws + 1048576;            // 16384*64
    unsigned short* vtg = ws + 2097152;            // 8*64*2048
    unsigned short* wt  = ws + 3145728;            // 3*64*768

    wt_kernel<<<576, 256, 0, stream>>>(Wq, Wk, Wv, wt);
    proj_kernel<<<3072, 64, 0, stream>>>(x, wt, qg, kg, vtg);
    attn_kernel<<<512, 128, 0, stream>>>(qg, kg, vtg, out);
}

// Round 6
// 97.868 us; speedup vs baseline: 2.0255x; 1.2734x over previous
//
#include <hip/hip_runtime.h>
#include <hip/hip_bf16.h>

// Head: x[8,2048,768] fp32; Wk,Wq,Wv [768,64] fp32 -> out[8,2048,64] fp32
// q=xWq k=xWk v=xWv; att=softmax(q k^T/8); out=att v   (no causal mask)
//
// R6: kill the per-iteration softmax chain.
//  - attn: swapped QK^T (S^T = mfma(K, Q)) -> lane-local softmax (2 shfl),
//    P already in mfma_16x16x16 B-frag layout -> PV with zero shuffles/LDS.
//    512 blocks x 4 key-split waves (wave = 32 q x 512 keys), reg prefetch,
//    defer-max, Q pre-scaled; one LDS combine at the end.
//  - proj: 512 blocks x 4 waves (2 row-tiles x 2 K-halves), f32 LDS combine,
//    per-wave repack epilogue; x read once, coalesced.

#define SEQ   2048
#define CEMB  768
// 0.125 (1/sqrt(64)) * log2(e): folded into q at proj epilogue
#define SCL 0.18033688011112042f
#define THR 11.0f   // defer-max threshold in exp2 units (~e^7.6)

typedef __attribute__((ext_vector_type(4))) float f32x4;
typedef __attribute__((ext_vector_type(4))) float fvec4;
typedef __attribute__((ext_vector_type(8))) short short8;
typedef __attribute__((ext_vector_type(4))) short short4v;
typedef __attribute__((ext_vector_type(2))) unsigned int u32x2;
typedef __attribute__((ext_vector_type(4))) unsigned int u32x4;

#define MFMA32 __builtin_amdgcn_mfma_f32_16x16x32_bf16

__device__ __forceinline__ unsigned short f2bf(float f) {
    unsigned int u = __builtin_bit_cast(unsigned int, f);
    u += 0x7fffu + ((u >> 16) & 1u);   // RNE
    return (unsigned short)(u >> 16);
}
// pack two floats to bf16x2 (round-to-nearest, ties-away): cheap (5 ops)
__device__ __forceinline__ unsigned int pack_bf2(float lo, float hi) {
    unsigned int ulo = __builtin_bit_cast(unsigned int, lo);
    unsigned int uhi = __builtin_bit_cast(unsigned int, hi);
    return ((uhi + 0x8000u) & 0xffff0000u) | ((ulo + 0x8000u) >> 16);
}

// ---------------- kernel 1: W -> W^T bf16  (wt[3][64][768]) ----------------
__global__ void wt_kernel(const float* __restrict__ Wq, const float* __restrict__ Wk,
                          const float* __restrict__ Wv, unsigned short* __restrict__ wt) {
    int idx = blockIdx.x * 256 + threadIdx.x;   // 3*64*768 = 147456
    int o = idx / 49152;
    int r = idx % 49152;
    int n = r / 768;
    int k = r % 768;
    const float* W = (o == 0) ? Wq : (o == 1) ? Wk : Wv;
    wt[idx] = f2bf(W[k * 64 + n]);
}

// ---- kernel 2: proj, 4 waves = 2 row-tiles x 2 K-halves, LDS combine -----
__global__ __launch_bounds__(256, 2) void proj_kernel(
        const float* __restrict__ x, const unsigned short* __restrict__ wt,
        unsigned short* __restrict__ qg, unsigned short* __restrict__ kg,
        unsigned short* __restrict__ vtg) {
    __shared__ __align__(16) float pc[2][3][16][64];            // 24 KB partials
    __shared__ __align__(16) unsigned short scratch[2][1280];   // 5 KB repack

    const int tid = threadIdx.x;
    const int lane = tid & 63;
    const int wv = tid >> 6;
    const int rw = wv >> 1;     // row-tile 0/1
    const int kw = wv & 1;      // K-half 0/1
    const int l15 = lane & 15;
    const int lq = lane >> 4;
    const int row0 = blockIdx.x * 32 + rw * 16;

    f32x4 acc[3][4];
    #pragma unroll
    for (int o = 0; o < 3; ++o)
        #pragma unroll
        for (int f = 0; f < 4; ++f) acc[o][f] = f32x4{0.f, 0.f, 0.f, 0.f};

    const float* xr = &x[(size_t)(row0 + l15) * CEMB + kw * 384 + lq * 8];

    #pragma unroll
    for (int s = 0; s < 6; ++s) {
        const int k0 = s * 64;
        fvec4 x0 = *reinterpret_cast<const fvec4*>(xr + k0);
        fvec4 x1 = *reinterpret_cast<const fvec4*>(xr + k0 + 4);
        fvec4 x2 = *reinterpret_cast<const fvec4*>(xr + k0 + 32);
        fvec4 x3 = *reinterpret_cast<const fvec4*>(xr + k0 + 36);
        short8 a0, a1;
        #pragma unroll
        for (int j = 0; j < 4; ++j) {
            a0[j]     = (short)f2bf(x0[j]);
            a0[4 + j] = (short)f2bf(x1[j]);
            a1[j]     = (short)f2bf(x2[j]);
            a1[4 + j] = (short)f2bf(x3[j]);
        }
        #pragma unroll
        for (int o = 0; o < 3; ++o) {
            #pragma unroll
            for (int f = 0; f < 4; ++f) {
                const unsigned short* wp =
                    &wt[o * 49152 + (f * 16 + l15) * CEMB + kw * 384 + k0 + lq * 8];
                short8 b0 = *reinterpret_cast<const short8*>(wp);
                short8 b1 = *reinterpret_cast<const short8*>(wp + 32);
                acc[o][f] = MFMA32(a0, b0, acc[o][f], 0, 0, 0);
                acc[o][f] = MFMA32(a1, b1, acc[o][f], 0, 0, 0);
            }
        }
    }

    if (kw == 1) {
        #pragma unroll
        for (int o = 0; o < 3; ++o)
            #pragma unroll
            for (int f = 0; f < 4; ++f)
                #pragma unroll
                for (int r = 0; r < 4; ++r)
                    pc[rw][o][lq * 4 + r][f * 16 + l15] = acc[o][f][r];
    }
    __syncthreads();
    if (kw == 0) {
        #pragma unroll
        for (int o = 0; o < 3; ++o)
            #pragma unroll
            for (int f = 0; f < 4; ++f)
                #pragma unroll
                for (int r = 0; r < 4; ++r)
                    acc[o][f][r] += pc[rw][o][lq * 4 + r][f * 16 + l15];

        // q, k: repack in wave-local scratch (in-order LDS per wave) -> 16B stores
        unsigned short (*sq)[80] = reinterpret_cast<unsigned short (*)[80]>(&scratch[rw][0]);
        #pragma unroll
        for (int o = 0; o < 2; ++o) {
            const float sc = o ? 1.f : SCL;   // fold softmax scale into q
            #pragma unroll
            for (int f = 0; f < 4; ++f)
                #pragma unroll
                for (int r = 0; r < 4; ++r)
                    sq[lq * 4 + r][f * 16 + l15] = f2bf(acc[o][f][r] * sc);
            unsigned short* dst = o ? kg : qg;
            #pragma unroll
            for (int i = 0; i < 2; ++i) {
                int chunk = lane + 64 * i;
                int m = chunk >> 3;
                int c0 = (chunk & 7) * 8;
                *reinterpret_cast<short8*>(&dst[(size_t)(row0 + m) * 64 + c0]) =
                    *reinterpret_cast<const short8*>(&sq[m][c0]);
            }
        }
        // v transposed -> vtg[b][h][t]
        unsigned short (*lv)[20] = reinterpret_cast<unsigned short (*)[20]>(&scratch[rw][0]);
        #pragma unroll
        for (int f = 0; f < 4; ++f)
            #pragma unroll
            for (int r = 0; r < 4; ++r)
                lv[f * 16 + l15][lq * 4 + r] = f2bf(acc[2][f][r]);
        const int bb = row0 >> 11;
        const int t0 = row0 & 2047;
        unsigned short* vp = &vtg[(size_t)bb * 64 * SEQ + (size_t)lane * SEQ + t0];
        *reinterpret_cast<short8*>(vp)     = *reinterpret_cast<const short8*>(&lv[lane][0]);
        *reinterpret_cast<short8*>(vp + 8) = *reinterpret_cast<const short8*>(&lv[lane][8]);
    }
}

// ---- kernel 3: flash attention, swapped-QK lane-local softmax ------------
#define LOADK(DST, T) do {                                                          \
    _Pragma("unroll")                                                               \
    for (int kb_ = 0; kb_ < 4; ++kb_) {                                             \
        const unsigned short* kp_ = kbase + (size_t)((T) * 64 + kb_ * 16 + l15) * 64; \
        DST[kb_ * 2]     = *reinterpret_cast<const short8*>(kp_ + lq * 8);          \
        DST[kb_ * 2 + 1] = *reinterpret_cast<const short8*>(kp_ + 32 + lq * 8);     \
    }                                                                               \
} while (0)

#if __has_builtin(__builtin_amdgcn_mfma_f32_16x16x16bf16_1k)
#define HAVE_MFMA16 1
#define MFMA16 __builtin_amdgcn_mfma_f32_16x16x16bf16_1k
#else
#define HAVE_MFMA16 0
#endif

#define ITER(KC, KN, T) do {                                                        \
    if ((T) + 1 < 8) LOADK(KN, (T) + 1);                                            \
    /* V fragments for tile T (used after softmax -> latency hidden) */             \
    PVLOAD(T);                                                                      \
    f32x4 st0[4], st1[4];                                                           \
    _Pragma("unroll")                                                               \
    for (int kb = 0; kb < 4; ++kb) {                                                \
        f32x4 z = {0.f, 0.f, 0.f, 0.f};                                             \
        st0[kb] = MFMA32(KC[kb * 2], bq00, z, 0, 0, 0);                             \
        st0[kb] = MFMA32(KC[kb * 2 + 1], bq01, st0[kb], 0, 0, 0);                   \
        st1[kb] = MFMA32(KC[kb * 2], bq10, z, 0, 0, 0);                             \
        st1[kb] = MFMA32(KC[kb * 2 + 1], bq11, st1[kb], 0, 0, 0);                   \
    }                                                                               \
    /* lane-local max over 16 vals + 2 shfl across the 4-lane q-group */            \
    f32x4 mx0 = vmax4(vmax4(st0[0], st0[1]), vmax4(st0[2], st0[3]));                \
    f32x4 mx1 = vmax4(vmax4(st1[0], st1[1]), vmax4(st1[2], st1[3]));                \
    float p0 = fmaxf(fmaxf(mx0[0], mx0[1]), fmaxf(mx0[2], mx0[3]));                 \
    float p1 = fmaxf(fmaxf(mx1[0], mx1[1]), fmaxf(mx1[2], mx1[3]));                 \
    p0 = fmaxf(p0, __shfl_xor(p0, 16)); p0 = fmaxf(p0, __shfl_xor(p0, 32));         \
    p1 = fmaxf(p1, __shfl_xor(p1, 16)); p1 = fmaxf(p1, __shfl_xor(p1, 32));         \
    if (__any((p0 > m0 + THR) || (p1 > m1 + THR))) {                                \
        float mn0 = fmaxf(m0, p0), mn1 = fmaxf(m1, p1);                             \
        float al0 = exp2f(m0 - mn0), al1 = exp2f(m1 - mn1);                         \
        m0 = mn0; m1 = mn1; l0 *= al0; l1 *= al1;                                   \
        _Pragma("unroll")                                                           \
        for (int hb = 0; hb < 4; ++hb) {                                            \
            _Pragma("unroll")                                                       \
            for (int r = 0; r < 4; ++r) { acc0[hb][r] *= al0; acc1[hb][r] *= al1; } \
        }                                                                           \
    }                                                                               \
    unsigned int w0[4][2], w1[4][2];                                                \
    _Pragma("unroll")                                                               \
    for (int kb = 0; kb < 4; ++kb) {                                                \
        float e0 = exp2f(st0[kb][0] - m0), e1 = exp2f(st0[kb][1] - m0);             \
        float e2 = exp2f(st0[kb][2] - m0), e3 = exp2f(st0[kb][3] - m0);             \
        l0 += (e0 + e1) + (e2 + e3);                                                \
        w0[kb][0] = pack_bf2(e0, e1); w0[kb][1] = pack_bf2(e2, e3);                 \
        float g0 = exp2f(st1[kb][0] - m1), g1 = exp2f(st1[kb][1] - m1);             \
        float g2 = exp2f(st1[kb][2] - m1), g3 = exp2f(st1[kb][3] - m1);             \
        l1 += (g0 + g1) + (g2 + g3);                                                \
        w1[kb][0] = pack_bf2(g0, g1); w1[kb][1] = pack_bf2(g2, g3);                 \
    }                                                                               \
    PVACC(w0, acc0); PVACC(w1, acc1);                                               \
} while (0)

#if HAVE_MFMA16
// P frag (keys kb*16+lq*4+{0..3}, q=l15) is exactly the 16x16x16 B layout.
#define PVLOAD(T)                                                                   \
    short4v va[16];                                                                 \
    _Pragma("unroll")                                                               \
    for (int hb_ = 0; hb_ < 4; ++hb_) {                                             \
        const unsigned short* vr_ = vbase + (size_t)(hb_ * 16 + l15) * SEQ + (T) * 64; \
        _Pragma("unroll")                                                           \
        for (int kb_ = 0; kb_ < 4; ++kb_)                                           \
            va[hb_ * 4 + kb_] =                                                     \
                *reinterpret_cast<const short4v*>(vr_ + kb_ * 16 + lq * 4);         \
    }
#define PVACC(W, ACC) do {                                                          \
    _Pragma("unroll")                                                               \
    for (int hb = 0; hb < 4; ++hb) {                                                \
        f32x4 a = ACC[hb];                                                          \
        _Pragma("unroll")                                                           \
        for (int kb = 0; kb < 4; ++kb) {                                            \
            u32x2 uv; uv[0] = W[kb][0]; uv[1] = W[kb][1];                           \
            a = MFMA16(va[hb * 4 + kb], __builtin_bit_cast(short4v, uv), a, 0, 0, 0); \
        }                                                                           \
        ACC[hb] = a;                                                                \
    }                                                                               \
} while (0)
#else
// Fallback: redistribute P to 16x16x32 B layout with 2 shfl + select per word.
#define PVLOAD(T)                                                                   \
    short8 va[8];                                                                   \
    _Pragma("unroll")                                                               \
    for (int hb_ = 0; hb_ < 4; ++hb_) {                                             \
        const unsigned short* vr_ = vbase + (size_t)(hb_ * 16 + l15) * SEQ + (T) * 64; \
        _Pragma("unroll")                                                           \
        for (int h_ = 0; h_ < 2; ++h_)                                              \
            va[hb_ * 2 + h_] =                                                      \
                *reinterpret_cast<const short8*>(vr_ + h_ * 32 + lq * 8);           \
    }
#define PVACC(W, ACC) do {                                                          \
    _Pragma("unroll")                                                               \
    for (int h = 0; h < 2; ++h) {                                                   \
        u32x4 bw;                                                                   \
        _Pragma("unroll")                                                           \
        for (int mw = 0; mw < 4; ++mw) {                                            \
            int src = l15 + ((((lq & 1) * 2) + (mw >> 1)) << 4);                    \
            unsigned int r1 = (unsigned int)__shfl((int)W[h * 2][mw & 1], src);     \
            unsigned int r2 = (unsigned int)__shfl((int)W[h * 2 + 1][mw & 1], src); \
            bw[mw] = (lq >> 1) ? r2 : r1;                                           \
        }                                                                           \
        short8 bp = __builtin_bit_cast(short8, bw);                                 \
        _Pragma("unroll")                                                           \
        for (int hb = 0; hb < 4; ++hb)                                              \
            ACC[hb] = MFMA32(va[hb * 2 + h], bp, ACC[hb], 0, 0, 0);                 \
    }                                                                               \
} while (0)
#endif

__device__ __forceinline__ f32x4 vmax4(f32x4 a, f32x4 b) {
    f32x4 r;
    r[0] = fmaxf(a[0], b[0]); r[1] = fmaxf(a[1], b[1]);
    r[2] = fmaxf(a[2], b[2]); r[3] = fmaxf(a[3], b[3]);
    return r;
}

__global__ __launch_bounds__(256, 2) void attn_kernel(
        const unsigned short* __restrict__ qg, const unsigned short* __restrict__ kg,
        const unsigned short* __restrict__ vtg, float* __restrict__ out) {
    __shared__ __align__(16) float oF[4][32][64];   // 32 KB
    __shared__ float mF[4][32];
    __shared__ float lF[4][32];

    const int tid = threadIdx.x;
    const int lane = tid & 63;
    const int kw = tid >> 6;          // key-split wave: keys [kw*512, +512)
    const int l15 = lane & 15;
    const int lq = lane >> 4;

    // XCD swizzle (512 % 8 == 0 -> bijective): one batch per XCD
    const int swz = (blockIdx.x & 7) * 64 + (blockIdx.x >> 3);
    const int b = swz >> 6;           // batch
    const int qt = swz & 63;          // 32-row q tile
    const size_t qrow0 = (size_t)b * SEQ + (size_t)qt * 32;

    const unsigned short* kbase = kg + ((size_t)b * SEQ + (size_t)kw * 512) * 64;
    const unsigned short* vbase = vtg + (size_t)b * 64 * SEQ + (size_t)kw * 512;

    // Q as B-operand (pre-scaled by SCL in proj): lane holds Q[q=l15][d slice]
    const short8 bq00 = *reinterpret_cast<const short8*>(&qg[(qrow0 + l15) * 64 + lq * 8]);
    const short8 bq01 = *reinterpret_cast<const short8*>(&qg[(qrow0 + l15) * 64 + 32 + lq * 8]);
    const short8 bq10 = *reinterpret_cast<const short8*>(&qg[(qrow0 + 16 + l15) * 64 + lq * 8]);
    const short8 bq11 = *reinterpret_cast<const short8*>(&qg[(qrow0 + 16 + l15) * 64 + 32 + lq * 8]);

    f32x4 acc0[4], acc1[4];   // out^T: acc[hb][r] = out[q][hb*16+lq*4+r]
    #pragma unroll
    for (int hb = 0; hb < 4; ++hb) {
        acc0[hb] = f32x4{0.f, 0.f, 0.f, 0.f};
        acc1[hb] = f32x4{0.f, 0.f, 0.f, 0.f};
    }
    float m0 = -3e38f, m1 = -3e38f, l0 = 0.f, l1 = 0.f;

    short8 kaA[8], kaB[8];
    LOADK(kaA, 0);
    #pragma unroll
    for (int it = 0; it < 8; it += 2) {
        ITER(kaA, kaB, it);
        ITER(kaB, kaA, it + 1);
    }

    // reduce l across the 4-lane q-group (disjoint key subsets)
    l0 += __shfl_xor(l0, 16); l0 += __shfl_xor(l0, 32);
    l1 += __shfl_xor(l1, 16); l1 += __shfl_xor(l1, 32);

    mF[kw][l15] = m0; mF[kw][16 + l15] = m1;
    lF[kw][l15] = l0; lF[kw][16 + l15] = l1;
    #pragma unroll
    for (int hb = 0; hb < 4; ++hb)
        #pragma unroll
        for (int r = 0; r < 4; ++r) {
            oF[kw][l15][hb * 16 + lq * 4 + r] = acc0[hb][r];
            oF[kw][16 + l15][hb * 16 + lq * 4 + r] = acc1[hb][r];
        }
    __syncthreads();

    // combine 4 key-split partials: 256 thr = 32 rows x 8 h-segments
    const int row = tid >> 3;
    const int hs = (tid & 7) * 8;
    float M = fmaxf(fmaxf(mF[0][row], mF[1][row]), fmaxf(mF[2][row], mF[3][row]));
    float L = 0.f;
    fvec4 s0 = {0.f, 0.f, 0.f, 0.f}, s1 = {0.f, 0.f, 0.f, 0.f};
    #pragma unroll
    for (int w = 0; w < 4; ++w) {
        float e = exp2f(mF[w][row] - M);
        L += lF[w][row] * e;
        s0 += e * *reinterpret_cast<const fvec4*>(&oF[w][row][hs]);
        s1 += e * *reinterpret_cast<const fvec4*>(&oF[w][row][hs + 4]);
    }
    float inv = 1.0f / L;
    *reinterpret_cast<fvec4*>(&out[(qrow0 + row) * 64 + hs]) = s0 * inv;
    *reinterpret_cast<fvec4*>(&out[(qrow0 + row) * 64 + hs + 4]) = s1 * inv;
}

extern "C" void kernel_launch(void* const* d_in, const int* in_sizes, int n_in,
                              void* d_out, int out_size, void* d_ws, size_t ws_size,
                              hipStream_t stream) {
    (void)in_sizes; (void)n_in; (void)out_size; (void)ws_size;
    const float* x  = (const float*)d_in[0];
    const float* Wk = (const float*)d_in[1];   // setup_inputs order: x, Wk, Wq, Wv
    const float* Wq = (const float*)d_in[2];
    const float* Wv = (const float*)d_in[3];
    float* out = (float*)d_out;

    unsigned short* ws = (unsigned short*)d_ws;
    unsigned short* qg  = ws;                      // 16384*64
    unsigned short* kg  = ws + 1048576;            // 16384*64
    unsigned short* vtg = ws + 2097152;            // 8*64*2048
    unsigned short* wt  = ws + 3145728;            // 3*64*768

    wt_kernel<<<576, 256, 0, stream>>>(Wq, Wk, Wv, wt);
    proj_kernel<<<512, 256, 0, stream>>>(x, wt, qg, kg, vtg);
    attn_kernel<<<512, 256, 0, stream>>>(qg, kg, vtg, out);
}